// Round 24
// baseline (235.528 us; speedup 1.0000x reference)
//
#include <hip/hip_runtime.h>
#include <hip/hip_bf16.h>
#include <math.h>

// Problem constants
#define B_ 4
#define S_ 2048
#define D_ 1024
#define H_ 16
#define DH_ 64
#define INNER_ 1024   // H_*DH_
#define N3_ 3072      // 3*INNER_
#define ROWS_ 8192    // B_*S_

typedef __attribute__((ext_vector_type(8))) short short8;
typedef __attribute__((ext_vector_type(8))) _Float16 half8;
typedef __attribute__((ext_vector_type(4))) _Float16 half4;
typedef __attribute__((ext_vector_type(4))) float f32x4;

#define QSCALE_ (0.125f * 1.44269504088896f)   // 1/sqrt(64) * log2(e)

#if __has_builtin(__builtin_amdgcn_exp2f)
#define EXP2N(x) __builtin_amdgcn_exp2f(x)
#else
#define EXP2N(x) exp2f(x)
#endif

__device__ __forceinline__ ushort f16rne(float x) {
    _Float16 h = (_Float16)x;
    return *reinterpret_cast<ushort*>(&h);
}

// XOR-swizzled byte offset into a row-major [.][64] 16-bit tile (128B rows).
__device__ __forceinline__ int swz(int row, int colByte) {
    return row * 128 + (colByte ^ ((row & 7) << 4));
}

// Bijective XCD-aware block remap (T1); nwg % 8 == 0 on both GEMM grids.
__device__ __forceinline__ void xcd_remap(int& bx, int& by) {
    const int gx  = gridDim.x;
    const int nwg = gx * gridDim.y;
    const int bid = blockIdx.y * gx + blockIdx.x;
    const int swzid = (bid & 7) * (nwg >> 3) + (bid >> 3);
    bx = swzid % gx;
    by = swzid / gx;
}

// ---------------------------------------------------------------------------
// LayerNorm: one block (256 threads) per row of 1024 floats -> f16.
// ---------------------------------------------------------------------------
__global__ __launch_bounds__(256) void ln_kernel(const float* __restrict__ x,
                                                 const float* __restrict__ gamma,
                                                 const float* __restrict__ beta,
                                                 ushort* __restrict__ xn_f) {
    const int row = blockIdx.x;
    const int tid = threadIdx.x;
    const float4 v = ((const float4*)(x + (size_t)row * D_))[tid];
    float s  = v.x + v.y + v.z + v.w;
    float ss = v.x * v.x + v.y * v.y + v.z * v.z + v.w * v.w;
    #pragma unroll
    for (int off = 32; off > 0; off >>= 1) {
        s  += __shfl_down(s, off);
        ss += __shfl_down(ss, off);
    }
    __shared__ float red[8];
    const int wave = tid >> 6, lane = tid & 63;
    if (lane == 0) { red[wave] = s; red[4 + wave] = ss; }
    __syncthreads();
    const float S  = red[0] + red[1] + red[2] + red[3];
    const float SS = red[4] + red[5] + red[6] + red[7];
    const float mu  = S * (1.0f / D_);
    const float var = SS * (1.0f / D_) - mu * mu;
    const float rs  = rsqrtf(var + 1e-5f);
    const float4 g  = ((const float4*)gamma)[tid];
    const float4 bb = ((const float4*)beta)[tid];
    const float o0 = (v.x - mu) * rs * g.x + bb.x;
    const float o1 = (v.y - mu) * rs * g.y + bb.y;
    const float o2 = (v.z - mu) * rs * g.z + bb.z;
    const float o3 = (v.w - mu) * rs * g.w + bb.w;
    *(ushort4*)(xn_f + (size_t)row * D_ + tid * 4) =
        make_ushort4(f16rne(o0), f16rne(o1), f16rne(o2), f16rne(o3));
}

// ---------------------------------------------------------------------------
// Weight transpose: W [K][N] fp32 -> T [N][K] f16.
// ---------------------------------------------------------------------------
__global__ __launch_bounds__(256) void wtrans_kernel(const float* __restrict__ W,
                                                     ushort* __restrict__ Tf,
                                                     int K, int N) {
    __shared__ float tile[64][68];
    const int tid = threadIdx.x;
    const int n0 = blockIdx.x * 64, k0 = blockIdx.y * 64;
    const int kr = tid >> 4, nc = (tid & 15) * 4;
    #pragma unroll
    for (int li = 0; li < 4; ++li) {
        const int k = kr + li * 16;
        *(float4*)&tile[k][nc] = *(const float4*)(W + (size_t)(k0 + k) * N + n0 + nc);
    }
    __syncthreads();
    const int nl = tid >> 2;
    const int ks = (tid & 3) * 16;
    ushort hbuf[16];
    #pragma unroll
    for (int i = 0; i < 16; ++i) hbuf[i] = f16rne(tile[ks + i][nl]);
    ushort* th = Tf + (size_t)(n0 + nl) * K + k0 + ks;
    #pragma unroll
    for (int i = 0; i < 4; ++i)
        *(ushort4*)(th + i * 4) = make_ushort4(hbuf[i*4], hbuf[i*4+1], hbuf[i*4+2], hbuf[i*4+3]);
}

// ---------------------------------------------------------------------------
// f16 MFMA GEMM (out-proj): C[M,N] = A[M,K] @ B^T[N,K] + bias, fp32 C.
// ---------------------------------------------------------------------------
__global__ __launch_bounds__(256) void gemm_f16_kernel(
        const ushort* __restrict__ Af, const ushort* __restrict__ Bf,
        float* __restrict__ C, int M, int N, int K,
        const float* __restrict__ bias) {
    __shared__ __align__(16) ushort As[128 * 64];
    __shared__ __align__(16) ushort Bs[128 * 64];
    const int tid  = threadIdx.x;
    const int lane = tid & 63;
    const int wv   = tid >> 6;
    const int lr = lane & 15, lg = lane >> 4;
    const int wr = wv >> 1, wc = wv & 1;
    int bx, by;
    xcd_remap(bx, by);
    const int m0 = by * 128, n0 = bx * 128;

    f32x4 acc[4][4];
    #pragma unroll
    for (int i = 0; i < 4; ++i)
        #pragma unroll
        for (int j = 0; j < 4; ++j) acc[i][j] = (f32x4){0.f, 0.f, 0.f, 0.f};

    const int sr = tid >> 3;
    const int ss = (tid & 7) * 16;

    for (int k0 = 0; k0 < K; k0 += 64) {
        __syncthreads();
        #pragma unroll
        for (int li = 0; li < 4; ++li) {
            const int r = sr + li * 32;
            const int off = swz(r, ss);
            *(uint4*)((char*)As + off) = *(const uint4*)(Af + (size_t)(m0 + r) * K + k0 + (ss >> 1));
            *(uint4*)((char*)Bs + off) = *(const uint4*)(Bf + (size_t)(n0 + r) * K + k0 + (ss >> 1));
        }
        __syncthreads();
        #pragma unroll
        for (int kc = 0; kc < 2; ++kc) {
            const int cb = kc * 64 + lg * 16;
            half8 a[4], b[4];
            #pragma unroll
            for (int i = 0; i < 4; ++i) {
                a[i] = *(half8*)((char*)As + swz(wr * 64 + i * 16 + lr, cb));
                b[i] = *(half8*)((char*)Bs + swz(wc * 64 + i * 16 + lr, cb));
            }
            __builtin_amdgcn_s_setprio(1);
            #pragma unroll
            for (int mi = 0; mi < 4; ++mi)
                #pragma unroll
                for (int ni = 0; ni < 4; ++ni)
                    acc[mi][ni] = __builtin_amdgcn_mfma_f32_16x16x32_f16(a[mi], b[ni], acc[mi][ni], 0, 0, 0);
            __builtin_amdgcn_s_setprio(0);
        }
    }

    #pragma unroll
    for (int mi = 0; mi < 4; ++mi) {
        #pragma unroll
        for (int rr = 0; rr < 4; ++rr) {
            const int row = m0 + wr * 64 + mi * 16 + lg * 4 + rr;
            float* crow = C + (size_t)row * N + n0 + wc * 64;
            #pragma unroll
            for (int ni = 0; ni < 4; ++ni) {
                const int col = ni * 16 + lr;
                float v = acc[mi][ni][rr];
                if (bias) v += bias[n0 + wc * 64 + col];
                crow[col] = v;
            }
        }
    }
}

// ---------------------------------------------------------------------------
// QKV GEMM (single f16) with FUSED RoPE + convert epilogue.
// Output per row (ushorts, base=row*3072): [0,1024)Qf [1024,2048)Kf [2048,3072)Vf
// ---------------------------------------------------------------------------
__global__ __launch_bounds__(256) void gemm_qkv_rope_kernel(
        const ushort* __restrict__ Af, const ushort* __restrict__ Bf,
        ushort* __restrict__ qkv16, int M, int N, int K,
        const float* __restrict__ cost, const float* __restrict__ sint) {
    __shared__ __align__(16) ushort As[128 * 64];
    __shared__ __align__(16) ushort Bs[128 * 64];
    const int tid  = threadIdx.x;
    const int lane = tid & 63;
    const int wv   = tid >> 6;
    const int lr = lane & 15, lg = lane >> 4;
    const int wr = wv >> 1, wc = wv & 1;
    int bx, by;
    xcd_remap(bx, by);
    const int m0 = by * 128, n0 = bx * 128;

    f32x4 acc[4][4];
    #pragma unroll
    for (int i = 0; i < 4; ++i)
        #pragma unroll
        for (int j = 0; j < 4; ++j) acc[i][j] = (f32x4){0.f, 0.f, 0.f, 0.f};

    const int sr = tid >> 3;
    const int ss = (tid & 7) * 16;

    for (int k0 = 0; k0 < K; k0 += 64) {
        __syncthreads();
        #pragma unroll
        for (int li = 0; li < 4; ++li) {
            const int r = sr + li * 32;
            const int off = swz(r, ss);
            *(uint4*)((char*)As + off) = *(const uint4*)(Af + (size_t)(m0 + r) * K + k0 + (ss >> 1));
            *(uint4*)((char*)Bs + off) = *(const uint4*)(Bf + (size_t)(n0 + r) * K + k0 + (ss >> 1));
        }
        __syncthreads();
        #pragma unroll
        for (int kc = 0; kc < 2; ++kc) {
            const int cb = kc * 64 + lg * 16;
            half8 a[4], b[4];
            #pragma unroll
            for (int i = 0; i < 4; ++i) {
                a[i] = *(half8*)((char*)As + swz(wr * 64 + i * 16 + lr, cb));
                b[i] = *(half8*)((char*)Bs + swz(wc * 64 + i * 16 + lr, cb));
            }
            __builtin_amdgcn_s_setprio(1);
            #pragma unroll
            for (int mi = 0; mi < 4; ++mi)
                #pragma unroll
                for (int ni = 0; ni < 4; ++ni)
                    acc[mi][ni] = __builtin_amdgcn_mfma_f32_16x16x32_f16(a[mi], b[ni], acc[mi][ni], 0, 0, 0);
            __builtin_amdgcn_s_setprio(0);
        }
    }

    // ---- fused RoPE + convert epilogue ----
    const int seg = n0 >> 10;                    // 0=Q, 1=K, 2=V (block-uniform)
    const int colbase = (n0 & 1023) + wc * 64;
    #pragma unroll
    for (int mi = 0; mi < 4; ++mi) {
        #pragma unroll
        for (int rr = 0; rr < 4; ++rr) {
            const int row = m0 + wr * 64 + mi * 16 + lg * 4 + rr;
            const int spos = row & (S_ - 1);
            ushort* wrow = qkv16 + (size_t)row * 3072 + seg * 1024 + colbase;
            if (seg < 2) {
                #pragma unroll
                for (int p = 0; p < 2; ++p) {
                    const int d2 = p * 16 + lr;
                    const float c = cost[spos * 32 + d2];
                    const float s = sint[spos * 32 + d2];
                    const float v1 = acc[mi][p][rr];
                    const float v2 = acc[mi][p + 2][rr];
                    float r1 = v1 * c - v2 * s;
                    float r2 = v1 * s + v2 * c;
                    if (seg == 0) { r1 *= QSCALE_; r2 *= QSCALE_; }
                    wrow[p * 16 + lr]      = f16rne(r1);
                    wrow[p * 16 + lr + 32] = f16rne(r2);
                }
            } else {
                #pragma unroll
                for (int ni = 0; ni < 4; ++ni)
                    wrow[ni * 16 + lr] = f16rne(acc[mi][ni][rr]);
            }
        }
    }
}

// ---------------------------------------------------------------------------
// RoPE cos/sin table: [S_][32] each.
// ---------------------------------------------------------------------------
__global__ __launch_bounds__(256) void rope_table_kernel(float* __restrict__ cost,
                                                         float* __restrict__ sint) {
    const int idx = blockIdx.x * 256 + threadIdx.x;
    const int s = idx >> 5;
    const int i = idx & 31;
    const float inv = powf(10000.0f, -(2.0f * (float)i) / 64.0f);
    const float f = (float)s * inv;
    float sv, cv;
    sincosf(f, &sv, &cv);
    cost[idx] = cv;
    sint[idx] = sv;
}

// ---------------------------------------------------------------------------
// Flash attention v19 = v18 (swapped-QK, register-resident P, 32KB dbuf,
// 1 barrier/tile) + VALU diet: v_cvt_pkrtz packs P (RTZ ~2^-11 perturbation,
// below noise floor) + T5 setprio around both MFMA clusters.
// ---------------------------------------------------------------------------
__global__ __launch_bounds__(256) void attn_mfma_kernel(const ushort* __restrict__ Q16,
                                                        ushort* __restrict__ att_f) {
    __shared__ __align__(16) ushort sK[2][64 * 64];
    __shared__ __align__(16) ushort sV[2][64 * 64];

    const int tid  = threadIdx.x;
    const int lane = tid & 63;
    const int wv   = tid >> 6;
    const int lr   = lane & 15;
    const int lg   = lane >> 4;

    const int bh = blockIdx.x;
    const int b  = bh >> 4;
    const int h  = bh & 15;
    const int q0 = blockIdx.y * 128;

    // Q fragments (2 row-tiles per wave); B operand of swapped QK mfma.
    half8 q[2][2];
    #pragma unroll
    for (int qt = 0; qt < 2; ++qt) {
        const int qrow = q0 + wv * 32 + qt * 16 + lr;
        const ushort* qp = Q16 + (size_t)(b * S_ + qrow) * 3072 + h * 64;
        #pragma unroll
        for (int kc = 0; kc < 2; ++kc)
            q[qt][kc] = *(const half8*)(qp + kc * 32 + lg * 8);
    }

    f32x4 accO[2][4];
    #pragma unroll
    for (int qt = 0; qt < 2; ++qt)
        #pragma unroll
        for (int t = 0; t < 4; ++t) accO[qt][t] = (f32x4){0.f, 0.f, 0.f, 0.f};
    float lrun[2] = {0.f, 0.f};   // partial l for q=lr (this lane's column)

    const int kr0 = tid >> 3, ksl = tid & 7;
    const int vjp = tid & 31;
    const int vd  = (tid >> 5) * 8;

    const ushort* kvbase = Q16 + (size_t)(b * S_) * 3072 + h * 64;

    short8 rk0, rk1, rv0, rv1;

#define LOADT(J0)                                                              \
    {                                                                          \
        const ushort* ktb = kvbase + (size_t)(J0) * 3072 + 1024;               \
        rk0 = *(const short8*)(ktb + (size_t)kr0 * 3072 + ksl * 8);            \
        rk1 = *(const short8*)(ktb + (size_t)(kr0 + 32) * 3072 + ksl * 8);     \
        const ushort* vtb = kvbase + (size_t)(J0) * 3072 + 2048;               \
        rv0 = *(const short8*)(vtb + (size_t)(2 * vjp) * 3072 + vd);           \
        rv1 = *(const short8*)(vtb + (size_t)(2 * vjp + 1) * 3072 + vd);       \
    }

#define WRITET(KP, VP)                                                         \
    {                                                                          \
        *(short8*)((char*)(KP) + swz(kr0, ksl * 16)) = rk0;                    \
        *(short8*)((char*)(KP) + swz(kr0 + 32, ksl * 16)) = rk1;               \
        _Pragma("unroll")                                                      \
        for (int i = 0; i < 8; ++i) {                                          \
            const int off = swz(vd + i, vjp * 4);                              \
            *(uint*)((char*)(VP) + off) = (uint)(ushort)rv0[i] | ((uint)(ushort)rv1[i] << 16); \
        }                                                                      \
    }

    LOADT(0)
    WRITET(sK[0], sV[0])

    const int NT = S_ / 64;
    for (int t = 0; t < NT; ++t) {
        const ushort* sKc = sK[t & 1];
        const ushort* sVc = sV[t & 1];
        ushort* sKn = sK[(t & 1) ^ 1];
        ushort* sVn = sV[(t & 1) ^ 1];

        __syncthreads();   // buf[t&1] writes visible; buf[(t+1)&1] fully consumed
        if (t + 1 < NT) LOADT((t + 1) * 64)

        // ---- QK^T swapped: accS[qt][tt] = K_tile(tt) x Q(qt)  ->  S^T
        f32x4 accS[2][4];
        #pragma unroll
        for (int qt = 0; qt < 2; ++qt)
            #pragma unroll
            for (int tt = 0; tt < 4; ++tt) accS[qt][tt] = (f32x4){0.f, 0.f, 0.f, 0.f};
        __builtin_amdgcn_s_setprio(1);
        #pragma unroll
        for (int kc = 0; kc < 2; ++kc) {
            #pragma unroll
            for (int tt = 0; tt < 4; ++tt) {
                const int off = swz(tt * 16 + lr, (kc * 32 + lg * 8) * 2);
                half8 kv = *(half8*)((char*)sKc + off);
                #pragma unroll
                for (int qt = 0; qt < 2; ++qt)
                    accS[qt][tt] = __builtin_amdgcn_mfma_f32_16x16x32_f16(kv, q[qt][kc], accS[qt][tt], 0, 0, 0);
            }
        }
        __builtin_amdgcn_s_setprio(0);

        // ---- softmax in-register: P A-frags via pkrtz (2 ops per half4)
        half4 pf[2][4];
        #pragma unroll
        for (int qt = 0; qt < 2; ++qt) {
            float ls = 0.f;
            #pragma unroll
            for (int tt = 0; tt < 4; ++tt) {
                const float p0 = EXP2N(accS[qt][tt][0]);
                const float p1 = EXP2N(accS[qt][tt][1]);
                const float p2 = EXP2N(accS[qt][tt][2]);
                const float p3 = EXP2N(accS[qt][tt][3]);
                ls += (p0 + p1) + (p2 + p3);
                const auto lo = __builtin_amdgcn_cvt_pkrtz(p0, p1);
                const auto hi = __builtin_amdgcn_cvt_pkrtz(p2, p3);
                half4 pk;
                pk[0] = (_Float16)lo[0]; pk[1] = (_Float16)lo[1];
                pk[2] = (_Float16)hi[0]; pk[3] = (_Float16)hi[1];
                pf[qt][tt] = pk;
            }
            lrun[qt] += ls;
        }

        // ---- PV from registers: 4 j-chunks x 4 dt, V frag read once (b64)
        __builtin_amdgcn_s_setprio(1);
        #pragma unroll
        for (int tt = 0; tt < 4; ++tt) {
            #pragma unroll
            for (int dt = 0; dt < 4; ++dt) {
                const int boff = swz(dt * 16 + lr, (tt * 16 + lg * 4) * 2);
                half4 vv = *(half4*)((char*)sVc + boff);
                accO[0][dt] = __builtin_amdgcn_mfma_f32_16x16x16f16(pf[0][tt], vv, accO[0][dt], 0, 0, 0);
                accO[1][dt] = __builtin_amdgcn_mfma_f32_16x16x16f16(pf[1][tt], vv, accO[1][dt], 0, 0, 0);
            }
        }
        __builtin_amdgcn_s_setprio(0);

        // write next tile into the other buffer (no second barrier needed)
        if (t + 1 < NT) WRITET(sKn, sVn)
    }

    // ---- l: reduce partials across the 4 lg groups -> every lane has L[q=lr]
    float Lq[2];
    #pragma unroll
    for (int qt = 0; qt < 2; ++qt) {
        float L = lrun[qt];
        L += __shfl_xor(L, 16);
        L += __shfl_xor(L, 32);
        Lq[qt] = L;
    }

    // ---- normalize + write f16
    #pragma unroll
    for (int qt = 0; qt < 2; ++qt) {
        #pragma unroll
        for (int r = 0; r < 4; ++r) {
            const float L = __shfl(Lq[qt], lg * 4 + r);
            const float inv_l = 1.0f / L;
            const int q_ = q0 + wv * 32 + qt * 16 + lg * 4 + r;
            const size_t ob = ((size_t)(b * S_ + q_)) * INNER_ + h * 64;
            #pragma unroll
            for (int dt = 0; dt < 4; ++dt)
                att_f[ob + dt * 16 + lr] = f16rne(accO[qt][dt][r] * inv_l);
        }
    }
#undef LOADT
#undef WRITET
}

// ---------------------------------------------------------------------------
// Launch
// ---------------------------------------------------------------------------
extern "C" void kernel_launch(void* const* d_in, const int* in_sizes, int n_in,
                              void* d_out, int out_size, void* d_ws, size_t ws_size,
                              hipStream_t stream) {
    const float* x        = (const float*)d_in[0];
    const float* w_qkv    = (const float*)d_in[1];
    const float* w_out    = (const float*)d_in[2];
    const float* b_out    = (const float*)d_in[3];
    const float* ln_gamma = (const float*)d_in[4];
    const float* ln_beta  = (const float*)d_in[5];
    float* out = (float*)d_out;

    char* wsb = (char*)d_ws;
    ushort* qkv16 = (ushort*)wsb;                                 // [0,48M) f16 layout
    ushort* xn_f  = (ushort*)(wsb + 100663296);                   // [96M,112M) f16
    ushort* att_f = xn_f;                                         // overlay (xn dead after QKV)
    ushort* wqT_f = (ushort*)(wsb + 134217728);                   // [128M,134M) f16
    ushort* woT_f = (ushort*)(wsb + 134217728 + 8388608);         // [136M,138M) f16
    float*  cost  = (float*)(wsb + 146800640);                    // [140M,140.5M)
    float*  sint  = cost + S_ * 32;

    // 1. LayerNorm -> f16
    ln_kernel<<<ROWS_, 256, 0, stream>>>(x, ln_gamma, ln_beta, xn_f);

    // 2. w_qkv transpose -> f16 ; rope table
    wtrans_kernel<<<dim3(N3_ / 64, D_ / 64), 256, 0, stream>>>(w_qkv, wqT_f, D_, N3_);
    rope_table_kernel<<<(S_ * 32) / 256, 256, 0, stream>>>(cost, sint);

    // 3. QKV projection (single f16, XCD-swizzled) + fused RoPE epilogue
    gemm_qkv_rope_kernel<<<dim3(N3_ / 128, ROWS_ / 128), 256, 0, stream>>>(
        xn_f, wqT_f, qkv16, ROWS_, N3_, D_, cost, sint);

    // 4. Attention (v19: pkrtz P-pack + setprio)
    attn_mfma_kernel<<<dim3(B_ * H_, S_ / 128), 256, 0, stream>>>(qkv16, att_f);

    // 5. w_out transpose -> f16
    wtrans_kernel<<<dim3(D_ / 64, D_ / 64), 256, 0, stream>>>(w_out, woT_f, D_, D_);

    // 6. Output projection (single f16, XCD-swizzled) + bias -> d_out
    gemm_f16_kernel<<<dim3(D_ / 128, ROWS_ / 128), 256, 0, stream>>>(
        att_f, woT_f, out, ROWS_, D_, INNER_, b_out);
}

// Round 25
// 228.307 us; speedup vs baseline: 1.0316x; 1.0316x over previous
//
#include <hip/hip_runtime.h>
#include <hip/hip_bf16.h>
#include <math.h>

// Problem constants
#define B_ 4
#define S_ 2048
#define D_ 1024
#define H_ 16
#define DH_ 64
#define INNER_ 1024   // H_*DH_
#define N3_ 3072      // 3*INNER_
#define ROWS_ 8192    // B_*S_

typedef __attribute__((ext_vector_type(8))) short short8;
typedef __attribute__((ext_vector_type(8))) _Float16 half8;
typedef __attribute__((ext_vector_type(4))) _Float16 half4;
typedef __attribute__((ext_vector_type(4))) float f32x4;

#define QSCALE_ (0.125f * 1.44269504088896f)   // 1/sqrt(64) * log2(e)

#if __has_builtin(__builtin_amdgcn_exp2f)
#define EXP2N(x) __builtin_amdgcn_exp2f(x)
#else
#define EXP2N(x) exp2f(x)
#endif

__device__ __forceinline__ ushort f16rne(float x) {
    _Float16 h = (_Float16)x;
    return *reinterpret_cast<ushort*>(&h);
}

// XOR-swizzled byte offset into a row-major [.][64] 16-bit tile (128B rows).
__device__ __forceinline__ int swz(int row, int colByte) {
    return row * 128 + (colByte ^ ((row & 7) << 4));
}

// Bijective XCD-aware block remap (T1); nwg % 8 == 0 on both GEMM grids.
__device__ __forceinline__ void xcd_remap(int& bx, int& by) {
    const int gx  = gridDim.x;
    const int nwg = gx * gridDim.y;
    const int bid = blockIdx.y * gx + blockIdx.x;
    const int swzid = (bid & 7) * (nwg >> 3) + (bid >> 3);
    bx = swzid % gx;
    by = swzid / gx;
}

// ---------------------------------------------------------------------------
// LayerNorm: one block (256 threads) per row of 1024 floats -> f16.
// ---------------------------------------------------------------------------
__global__ __launch_bounds__(256) void ln_kernel(const float* __restrict__ x,
                                                 const float* __restrict__ gamma,
                                                 const float* __restrict__ beta,
                                                 ushort* __restrict__ xn_f) {
    const int row = blockIdx.x;
    const int tid = threadIdx.x;
    const float4 v = ((const float4*)(x + (size_t)row * D_))[tid];
    float s  = v.x + v.y + v.z + v.w;
    float ss = v.x * v.x + v.y * v.y + v.z * v.z + v.w * v.w;
    #pragma unroll
    for (int off = 32; off > 0; off >>= 1) {
        s  += __shfl_down(s, off);
        ss += __shfl_down(ss, off);
    }
    __shared__ float red[8];
    const int wave = tid >> 6, lane = tid & 63;
    if (lane == 0) { red[wave] = s; red[4 + wave] = ss; }
    __syncthreads();
    const float S  = red[0] + red[1] + red[2] + red[3];
    const float SS = red[4] + red[5] + red[6] + red[7];
    const float mu  = S * (1.0f / D_);
    const float var = SS * (1.0f / D_) - mu * mu;
    const float rs  = rsqrtf(var + 1e-5f);
    const float4 g  = ((const float4*)gamma)[tid];
    const float4 bb = ((const float4*)beta)[tid];
    const float o0 = (v.x - mu) * rs * g.x + bb.x;
    const float o1 = (v.y - mu) * rs * g.y + bb.y;
    const float o2 = (v.z - mu) * rs * g.z + bb.z;
    const float o3 = (v.w - mu) * rs * g.w + bb.w;
    *(ushort4*)(xn_f + (size_t)row * D_ + tid * 4) =
        make_ushort4(f16rne(o0), f16rne(o1), f16rne(o2), f16rne(o3));
}

// ---------------------------------------------------------------------------
// Weight transpose: W [K][N] fp32 -> T [N][K] f16.
// ---------------------------------------------------------------------------
__global__ __launch_bounds__(256) void wtrans_kernel(const float* __restrict__ W,
                                                     ushort* __restrict__ Tf,
                                                     int K, int N) {
    __shared__ float tile[64][68];
    const int tid = threadIdx.x;
    const int n0 = blockIdx.x * 64, k0 = blockIdx.y * 64;
    const int kr = tid >> 4, nc = (tid & 15) * 4;
    #pragma unroll
    for (int li = 0; li < 4; ++li) {
        const int k = kr + li * 16;
        *(float4*)&tile[k][nc] = *(const float4*)(W + (size_t)(k0 + k) * N + n0 + nc);
    }
    __syncthreads();
    const int nl = tid >> 2;
    const int ks = (tid & 3) * 16;
    ushort hbuf[16];
    #pragma unroll
    for (int i = 0; i < 16; ++i) hbuf[i] = f16rne(tile[ks + i][nl]);
    ushort* th = Tf + (size_t)(n0 + nl) * K + k0 + ks;
    #pragma unroll
    for (int i = 0; i < 4; ++i)
        *(ushort4*)(th + i * 4) = make_ushort4(hbuf[i*4], hbuf[i*4+1], hbuf[i*4+2], hbuf[i*4+3]);
}

// ---------------------------------------------------------------------------
// f16 MFMA GEMM (out-proj): C[M,N] = A[M,K] @ B^T[N,K] + bias, fp32 C.
// ---------------------------------------------------------------------------
__global__ __launch_bounds__(256) void gemm_f16_kernel(
        const ushort* __restrict__ Af, const ushort* __restrict__ Bf,
        float* __restrict__ C, int M, int N, int K,
        const float* __restrict__ bias) {
    __shared__ __align__(16) ushort As[128 * 64];
    __shared__ __align__(16) ushort Bs[128 * 64];
    const int tid  = threadIdx.x;
    const int lane = tid & 63;
    const int wv   = tid >> 6;
    const int lr = lane & 15, lg = lane >> 4;
    const int wr = wv >> 1, wc = wv & 1;
    int bx, by;
    xcd_remap(bx, by);
    const int m0 = by * 128, n0 = bx * 128;

    f32x4 acc[4][4];
    #pragma unroll
    for (int i = 0; i < 4; ++i)
        #pragma unroll
        for (int j = 0; j < 4; ++j) acc[i][j] = (f32x4){0.f, 0.f, 0.f, 0.f};

    const int sr = tid >> 3;
    const int ss = (tid & 7) * 16;

    for (int k0 = 0; k0 < K; k0 += 64) {
        __syncthreads();
        #pragma unroll
        for (int li = 0; li < 4; ++li) {
            const int r = sr + li * 32;
            const int off = swz(r, ss);
            *(uint4*)((char*)As + off) = *(const uint4*)(Af + (size_t)(m0 + r) * K + k0 + (ss >> 1));
            *(uint4*)((char*)Bs + off) = *(const uint4*)(Bf + (size_t)(n0 + r) * K + k0 + (ss >> 1));
        }
        __syncthreads();
        #pragma unroll
        for (int kc = 0; kc < 2; ++kc) {
            const int cb = kc * 64 + lg * 16;
            half8 a[4], b[4];
            #pragma unroll
            for (int i = 0; i < 4; ++i) {
                a[i] = *(half8*)((char*)As + swz(wr * 64 + i * 16 + lr, cb));
                b[i] = *(half8*)((char*)Bs + swz(wc * 64 + i * 16 + lr, cb));
            }
            __builtin_amdgcn_s_setprio(1);
            #pragma unroll
            for (int mi = 0; mi < 4; ++mi)
                #pragma unroll
                for (int ni = 0; ni < 4; ++ni)
                    acc[mi][ni] = __builtin_amdgcn_mfma_f32_16x16x32_f16(a[mi], b[ni], acc[mi][ni], 0, 0, 0);
            __builtin_amdgcn_s_setprio(0);
        }
    }

    #pragma unroll
    for (int mi = 0; mi < 4; ++mi) {
        #pragma unroll
        for (int rr = 0; rr < 4; ++rr) {
            const int row = m0 + wr * 64 + mi * 16 + lg * 4 + rr;
            float* crow = C + (size_t)row * N + n0 + wc * 64;
            #pragma unroll
            for (int ni = 0; ni < 4; ++ni) {
                const int col = ni * 16 + lr;
                float v = acc[mi][ni][rr];
                if (bias) v += bias[n0 + wc * 64 + col];
                crow[col] = v;
            }
        }
    }
}

// ---------------------------------------------------------------------------
// QKV GEMM (single f16) with FUSED RoPE + convert epilogue.
// Output per row (ushorts, base=row*3072): [0,1024)Qf [1024,2048)Kf [2048,3072)Vf
// ---------------------------------------------------------------------------
__global__ __launch_bounds__(256) void gemm_qkv_rope_kernel(
        const ushort* __restrict__ Af, const ushort* __restrict__ Bf,
        ushort* __restrict__ qkv16, int M, int N, int K,
        const float* __restrict__ cost, const float* __restrict__ sint) {
    __shared__ __align__(16) ushort As[128 * 64];
    __shared__ __align__(16) ushort Bs[128 * 64];
    const int tid  = threadIdx.x;
    const int lane = tid & 63;
    const int wv   = tid >> 6;
    const int lr = lane & 15, lg = lane >> 4;
    const int wr = wv >> 1, wc = wv & 1;
    int bx, by;
    xcd_remap(bx, by);
    const int m0 = by * 128, n0 = bx * 128;

    f32x4 acc[4][4];
    #pragma unroll
    for (int i = 0; i < 4; ++i)
        #pragma unroll
        for (int j = 0; j < 4; ++j) acc[i][j] = (f32x4){0.f, 0.f, 0.f, 0.f};

    const int sr = tid >> 3;
    const int ss = (tid & 7) * 16;

    for (int k0 = 0; k0 < K; k0 += 64) {
        __syncthreads();
        #pragma unroll
        for (int li = 0; li < 4; ++li) {
            const int r = sr + li * 32;
            const int off = swz(r, ss);
            *(uint4*)((char*)As + off) = *(const uint4*)(Af + (size_t)(m0 + r) * K + k0 + (ss >> 1));
            *(uint4*)((char*)Bs + off) = *(const uint4*)(Bf + (size_t)(n0 + r) * K + k0 + (ss >> 1));
        }
        __syncthreads();
        #pragma unroll
        for (int kc = 0; kc < 2; ++kc) {
            const int cb = kc * 64 + lg * 16;
            half8 a[4], b[4];
            #pragma unroll
            for (int i = 0; i < 4; ++i) {
                a[i] = *(half8*)((char*)As + swz(wr * 64 + i * 16 + lr, cb));
                b[i] = *(half8*)((char*)Bs + swz(wc * 64 + i * 16 + lr, cb));
            }
            __builtin_amdgcn_s_setprio(1);
            #pragma unroll
            for (int mi = 0; mi < 4; ++mi)
                #pragma unroll
                for (int ni = 0; ni < 4; ++ni)
                    acc[mi][ni] = __builtin_amdgcn_mfma_f32_16x16x32_f16(a[mi], b[ni], acc[mi][ni], 0, 0, 0);
            __builtin_amdgcn_s_setprio(0);
        }
    }

    // ---- fused RoPE + convert epilogue ----
    const int seg = n0 >> 10;                    // 0=Q, 1=K, 2=V (block-uniform)
    const int colbase = (n0 & 1023) + wc * 64;
    #pragma unroll
    for (int mi = 0; mi < 4; ++mi) {
        #pragma unroll
        for (int rr = 0; rr < 4; ++rr) {
            const int row = m0 + wr * 64 + mi * 16 + lg * 4 + rr;
            const int spos = row & (S_ - 1);
            ushort* wrow = qkv16 + (size_t)row * 3072 + seg * 1024 + colbase;
            if (seg < 2) {
                #pragma unroll
                for (int p = 0; p < 2; ++p) {
                    const int d2 = p * 16 + lr;
                    const float c = cost[spos * 32 + d2];
                    const float s = sint[spos * 32 + d2];
                    const float v1 = acc[mi][p][rr];
                    const float v2 = acc[mi][p + 2][rr];
                    float r1 = v1 * c - v2 * s;
                    float r2 = v1 * s + v2 * c;
                    if (seg == 0) { r1 *= QSCALE_; r2 *= QSCALE_; }
                    wrow[p * 16 + lr]      = f16rne(r1);
                    wrow[p * 16 + lr + 32] = f16rne(r2);
                }
            } else {
                #pragma unroll
                for (int ni = 0; ni < 4; ++ni)
                    wrow[ni * 16 + lr] = f16rne(acc[mi][ni][rr]);
            }
        }
    }
}

// ---------------------------------------------------------------------------
// RoPE cos/sin table: [S_][32] each.
// ---------------------------------------------------------------------------
__global__ __launch_bounds__(256) void rope_table_kernel(float* __restrict__ cost,
                                                         float* __restrict__ sint) {
    const int idx = blockIdx.x * 256 + threadIdx.x;
    const int s = idx >> 5;
    const int i = idx & 31;
    const float inv = powf(10000.0f, -(2.0f * (float)i) / 64.0f);
    const float f = (float)s * inv;
    float sv, cv;
    sincosf(f, &sv, &cv);
    cost[idx] = cv;
    sint[idx] = sv;
}

// ---------------------------------------------------------------------------
// Flash attention v18 (round-22 champion, EXACT): swapped-QK (register-
// resident P via S^T C-layout == 16x16x16 A-frag), 32KB double-buffered K/V,
// ONE barrier per tile, native exp2, per-lane scalar l partials.
// Round-24 lesson: pkrtz repack + setprio-bracketed MFMA clusters REGRESSED
// (VGPR 80->92, VALUBusy +7, MfmaUtil -4) — compiler's own schedule wins.
// ---------------------------------------------------------------------------
__global__ __launch_bounds__(256) void attn_mfma_kernel(const ushort* __restrict__ Q16,
                                                        ushort* __restrict__ att_f) {
    __shared__ __align__(16) ushort sK[2][64 * 64];
    __shared__ __align__(16) ushort sV[2][64 * 64];

    const int tid  = threadIdx.x;
    const int lane = tid & 63;
    const int wv   = tid >> 6;
    const int lr   = lane & 15;
    const int lg   = lane >> 4;

    const int bh = blockIdx.x;
    const int b  = bh >> 4;
    const int h  = bh & 15;
    const int q0 = blockIdx.y * 128;

    // Q fragments (2 row-tiles per wave); B operand of swapped QK mfma.
    half8 q[2][2];
    #pragma unroll
    for (int qt = 0; qt < 2; ++qt) {
        const int qrow = q0 + wv * 32 + qt * 16 + lr;
        const ushort* qp = Q16 + (size_t)(b * S_ + qrow) * 3072 + h * 64;
        #pragma unroll
        for (int kc = 0; kc < 2; ++kc)
            q[qt][kc] = *(const half8*)(qp + kc * 32 + lg * 8);
    }

    f32x4 accO[2][4];
    #pragma unroll
    for (int qt = 0; qt < 2; ++qt)
        #pragma unroll
        for (int t = 0; t < 4; ++t) accO[qt][t] = (f32x4){0.f, 0.f, 0.f, 0.f};
    float lrun[2] = {0.f, 0.f};   // partial l for q=lr (this lane's column)

    const int kr0 = tid >> 3, ksl = tid & 7;
    const int vjp = tid & 31;
    const int vd  = (tid >> 5) * 8;

    const ushort* kvbase = Q16 + (size_t)(b * S_) * 3072 + h * 64;

    short8 rk0, rk1, rv0, rv1;

#define LOADT(J0)                                                              \
    {                                                                          \
        const ushort* ktb = kvbase + (size_t)(J0) * 3072 + 1024;               \
        rk0 = *(const short8*)(ktb + (size_t)kr0 * 3072 + ksl * 8);            \
        rk1 = *(const short8*)(ktb + (size_t)(kr0 + 32) * 3072 + ksl * 8);     \
        const ushort* vtb = kvbase + (size_t)(J0) * 3072 + 2048;               \
        rv0 = *(const short8*)(vtb + (size_t)(2 * vjp) * 3072 + vd);           \
        rv1 = *(const short8*)(vtb + (size_t)(2 * vjp + 1) * 3072 + vd);       \
    }

#define WRITET(KP, VP)                                                         \
    {                                                                          \
        *(short8*)((char*)(KP) + swz(kr0, ksl * 16)) = rk0;                    \
        *(short8*)((char*)(KP) + swz(kr0 + 32, ksl * 16)) = rk1;               \
        _Pragma("unroll")                                                      \
        for (int i = 0; i < 8; ++i) {                                          \
            const int off = swz(vd + i, vjp * 4);                              \
            *(uint*)((char*)(VP) + off) = (uint)(ushort)rv0[i] | ((uint)(ushort)rv1[i] << 16); \
        }                                                                      \
    }

    LOADT(0)
    WRITET(sK[0], sV[0])

    const int NT = S_ / 64;
    for (int t = 0; t < NT; ++t) {
        const ushort* sKc = sK[t & 1];
        const ushort* sVc = sV[t & 1];
        ushort* sKn = sK[(t & 1) ^ 1];
        ushort* sVn = sV[(t & 1) ^ 1];

        __syncthreads();   // buf[t&1] writes visible; buf[(t+1)&1] fully consumed
        if (t + 1 < NT) LOADT((t + 1) * 64)

        // ---- QK^T swapped: accS[qt][tt] = K_tile(tt) x Q(qt)  ->  S^T
        f32x4 accS[2][4];
        #pragma unroll
        for (int qt = 0; qt < 2; ++qt)
            #pragma unroll
            for (int tt = 0; tt < 4; ++tt) accS[qt][tt] = (f32x4){0.f, 0.f, 0.f, 0.f};
        #pragma unroll
        for (int kc = 0; kc < 2; ++kc) {
            #pragma unroll
            for (int tt = 0; tt < 4; ++tt) {
                const int off = swz(tt * 16 + lr, (kc * 32 + lg * 8) * 2);
                half8 kv = *(half8*)((char*)sKc + off);
                #pragma unroll
                for (int qt = 0; qt < 2; ++qt)
                    accS[qt][tt] = __builtin_amdgcn_mfma_f32_16x16x32_f16(kv, q[qt][kc], accS[qt][tt], 0, 0, 0);
            }
        }

        // ---- softmax in-register: P A-frags (16x16x16) built directly
        half4 pf[2][4];
        #pragma unroll
        for (int qt = 0; qt < 2; ++qt) {
            float ls = 0.f;
            #pragma unroll
            for (int tt = 0; tt < 4; ++tt) {
                const float p0 = EXP2N(accS[qt][tt][0]);
                const float p1 = EXP2N(accS[qt][tt][1]);
                const float p2 = EXP2N(accS[qt][tt][2]);
                const float p3 = EXP2N(accS[qt][tt][3]);
                ls += (p0 + p1) + (p2 + p3);
                half4 pk;
                pk[0] = (_Float16)p0; pk[1] = (_Float16)p1;
                pk[2] = (_Float16)p2; pk[3] = (_Float16)p3;
                pf[qt][tt] = pk;
            }
            lrun[qt] += ls;
        }

        // ---- PV from registers: 4 j-chunks x 4 dt, V frag read once (b64)
        #pragma unroll
        for (int tt = 0; tt < 4; ++tt) {
            #pragma unroll
            for (int dt = 0; dt < 4; ++dt) {
                const int boff = swz(dt * 16 + lr, (tt * 16 + lg * 4) * 2);
                half4 vv = *(half4*)((char*)sVc + boff);
                accO[0][dt] = __builtin_amdgcn_mfma_f32_16x16x16f16(pf[0][tt], vv, accO[0][dt], 0, 0, 0);
                accO[1][dt] = __builtin_amdgcn_mfma_f32_16x16x16f16(pf[1][tt], vv, accO[1][dt], 0, 0, 0);
            }
        }

        // write next tile into the other buffer (no second barrier needed)
        if (t + 1 < NT) WRITET(sKn, sVn)
    }

    // ---- l: reduce partials across the 4 lg groups -> every lane has L[q=lr]
    float Lq[2];
    #pragma unroll
    for (int qt = 0; qt < 2; ++qt) {
        float L = lrun[qt];
        L += __shfl_xor(L, 16);
        L += __shfl_xor(L, 32);
        Lq[qt] = L;
    }

    // ---- normalize + write f16
    #pragma unroll
    for (int qt = 0; qt < 2; ++qt) {
        #pragma unroll
        for (int r = 0; r < 4; ++r) {
            const float L = __shfl(Lq[qt], lg * 4 + r);
            const float inv_l = 1.0f / L;
            const int q_ = q0 + wv * 32 + qt * 16 + lg * 4 + r;
            const size_t ob = ((size_t)(b * S_ + q_)) * INNER_ + h * 64;
            #pragma unroll
            for (int dt = 0; dt < 4; ++dt)
                att_f[ob + dt * 16 + lr] = f16rne(accO[qt][dt][r] * inv_l);
        }
    }
#undef LOADT
#undef WRITET
}

// ---------------------------------------------------------------------------
// Launch
// ---------------------------------------------------------------------------
extern "C" void kernel_launch(void* const* d_in, const int* in_sizes, int n_in,
                              void* d_out, int out_size, void* d_ws, size_t ws_size,
                              hipStream_t stream) {
    const float* x        = (const float*)d_in[0];
    const float* w_qkv    = (const float*)d_in[1];
    const float* w_out    = (const float*)d_in[2];
    const float* b_out    = (const float*)d_in[3];
    const float* ln_gamma = (const float*)d_in[4];
    const float* ln_beta  = (const float*)d_in[5];
    float* out = (float*)d_out;

    char* wsb = (char*)d_ws;
    ushort* qkv16 = (ushort*)wsb;                                 // [0,48M) f16 layout
    ushort* xn_f  = (ushort*)(wsb + 100663296);                   // [96M,112M) f16
    ushort* att_f = xn_f;                                         // overlay (xn dead after QKV)
    ushort* wqT_f = (ushort*)(wsb + 134217728);                   // [128M,134M) f16
    ushort* woT_f = (ushort*)(wsb + 134217728 + 8388608);         // [136M,138M) f16
    float*  cost  = (float*)(wsb + 146800640);                    // [140M,140.5M)
    float*  sint  = cost + S_ * 32;

    // 1. LayerNorm -> f16
    ln_kernel<<<ROWS_, 256, 0, stream>>>(x, ln_gamma, ln_beta, xn_f);

    // 2. w_qkv transpose -> f16 ; rope table
    wtrans_kernel<<<dim3(N3_ / 64, D_ / 64), 256, 0, stream>>>(w_qkv, wqT_f, D_, N3_);
    rope_table_kernel<<<(S_ * 32) / 256, 256, 0, stream>>>(cost, sint);

    // 3. QKV projection (single f16, XCD-swizzled) + fused RoPE epilogue
    gemm_qkv_rope_kernel<<<dim3(N3_ / 128, ROWS_ / 128), 256, 0, stream>>>(
        xn_f, wqT_f, qkv16, ROWS_, N3_, D_, cost, sint);

    // 4. Attention (v18 champion: swapped-QK + 32KB dbuf, 1 barrier/tile)
    attn_mfma_kernel<<<dim3(B_ * H_, S_ / 128), 256, 0, stream>>>(qkv16, att_f);

    // 5. w_out transpose -> f16
    wtrans_kernel<<<dim3(D_ / 64, D_ / 64), 256, 0, stream>>>(w_out, woT_f, D_, D_);

    // 6. Output projection (single f16, XCD-swizzled) + bias -> d_out
    gemm_f16_kernel<<<dim3(D_ / 128, ROWS_ / 128), 256, 0, stream>>>(
        att_f, woT_f, out, ROWS_, D_, INNER_, b_out);
}